// Round 6
// baseline (225.125 us; speedup 1.0000x reference)
//
#include <hip/hip_runtime.h>
#include <math.h>

// Problem constants (fixed by reference)
#define GRIDN   14
#define BOXN    2
#define LABELN  20
#define ALL_BOX 10          // 5*BOXN
#define CCH     30          // ALL_BOX + LABELN channels per cell

// R13: LDS-free, barrier-free, m13-shape streaming kernel.
// R7-R12: five structurally distinct staged schedules (convoy, 4x occupancy,
// drain-free barrier, depth-2 counted-vmcnt reg pipeline, depth-3
// global_load_lds DMA) ALL deliver 2.4-2.8 TB/s. Decisive counter fact:
// cache-resident replay dispatches (hbm_bytes ~ 0) take the SAME 70-80 us
// as HBM dispatches -> the cap is in the CU request path under the staged/
// barriered structure, not in the memory system.
// R13 removes the structure instead of tuning it. Algebra: obj cells ~8%.
//   loss = SUM_allcells 0.5*(p4^2+p9^2)                      [preds stream]
//        + SUM_objcells (cell_loss(p,t) - 0.5*(p4^2+p9^2))   [rare gather]
// obj detection (t[ch4] > 0) rides the truths stream. The transpose (and
// with it all LDS staging and every barrier) disappears. The hot loop is
// exactly the m13 6.3 TB/s pattern: grid-stride float4, independent
// iterations, no fences, natural occupancy, one atomic per block.
#define NBLK  2048
#define NTHR  256
#define GSTRIDE (NBLK * NTHR)   // 524,288 threads, lane-contiguous float4

typedef float vfloat4 __attribute__((ext_vector_type(4)));

__global__ void yolo_zero_kernel(float* out, int n) {
    int i = blockIdx.x * blockDim.x + threadIdx.x;
    if (i < n) out[i] = 0.0f;
}

// Validated per-cell loss math (absmax 0 in rounds 1-12). Unchanged.
// Now reads the cell's 30+30 floats straight from global (L2/L3-warm).
__device__ __forceinline__ float cell_loss(const float* p, const float* t) {
#pragma clang fp contract(off)
    const float CELL = (float)(1.0 / (double)GRIDN);

    const float tx = t[0], ty = t[1], tw = t[2], th_ = t[3], tconf = t[4];
    const bool obj = tconf > 0.0f;

    const float tcx = CELL * tx, tcy = CELL * ty;
    const float thx = tw * 0.5f, thy = th_ * 0.5f;
    const float tltx = tcx - thx, tlty = tcy - thy;
    const float trbx = tcx + thx, trby = tcy + thy;
    const float ta = (trbx - tltx) * (trby - tlty);

    float iou[BOXN], conf[BOXN];
#pragma unroll
    for (int b = 0; b < BOXN; ++b) {
        const float bx = p[b * 5 + 0], by = p[b * 5 + 1];
        const float bw = p[b * 5 + 2], bh = p[b * 5 + 3];
        conf[b] = p[b * 5 + 4];
        const float pcx = CELL * bx, pcy = CELL * by;
        const float phx = bw * 0.5f, phy = bh * 0.5f;
        const float pltx = pcx - phx, plty = pcy - phy;
        const float prbx = pcx + phx, prby = pcy + phy;
        const float ltx = fmaxf(pltx, tltx), lty = fmaxf(plty, tlty);
        const float rbx = fminf(prbx, trbx), rby = fminf(prby, trby);
        const float whx = fmaxf(rbx - ltx, 0.0f);
        const float why = fmaxf(rby - lty, 0.0f);
        const float inter = whx * why;
        const float pa = (prbx - pltx) * (prby - plty);
        iou[b] = inter / (pa + ta - inter);
    }

    const float max_iou = fmaxf(iou[0], iou[1]);
    bool r1;
    if (iou[0] == iou[1]) r1 = !(conf[0] >= conf[1]);
    else                  r1 = !(iou[0] > iou[1]);

    const float rx = r1 ? p[5] : p[0];
    const float ry = r1 ? p[6] : p[1];
    const float rw = r1 ? p[7] : p[2];
    const float rh = r1 ? p[8] : p[3];
    const float rc = r1 ? p[9] : p[4];

    const float dcx = rx - tx;
    const float dcy = ry - ty;
    const float center = dcx * dcx + dcy * dcy;

    const float dsx = sqrtf(rw) - sqrtf(tw);
    const float dsy = sqrtf(rh) - sqrtf(th_);
    const float size = dsx * dsx + dsy * dsy;

    const float dconf = rc - max_iou;
    const float conf_resp = dconf * dconf;

    const float c_other = r1 ? conf[0] : conf[1];
    const float conf_noresp = c_other * c_other;

    const float conf_noobj = conf[0] * conf[0] + conf[1] * conf[1];

    float label = 0.0f;
#pragma unroll
    for (int k = ALL_BOX; k < CCH; ++k) {
        const float d = p[k] - t[k];
        label += d * d;
    }

    const float w  = obj ? 1.0f : 0.0f;
    const float nw = obj ? 0.0f : 1.0f;
    return w * (5.0f * (center + size) + conf_resp + 0.5f * conf_noresp + label)
         + nw * (0.5f * conf_noobj);
}

__global__ __launch_bounds__(256) void yolo_loss_kernel(
    const float* __restrict__ preds,
    const float* __restrict__ truths,
    float* __restrict__ out,
    int nf4)                        // float4 count per tensor (6,021,120)
{
#pragma clang fp contract(off)
    __shared__ float wsum[4];

    const int tid  = threadIdx.x;
    const int wave = tid >> 6;
    const int lane = tid & 63;
    const int gid  = blockIdx.x * NTHR + tid;

    const vfloat4* pp = (const vfloat4*)preds;
    const vfloat4* tp = (const vfloat4*)truths;

    float acc = 0.0f;

    // m13-shape hot loop: both streams, lane-contiguous float4, iterations
    // fully independent (no LDS, no barriers) -> compiler/HW free to keep
    // many loads in flight across 32 waves/CU.
    for (int idx = gid; idx < nf4; idx += GSTRIDE) {
        const vfloat4 pv = pp[idx];
        const vfloat4 tv = tp[idx];
        const int f  = idx * 4;        // flat float index (< 2^25, safe)
        const int c0 = f % 30;         // channel of element 0

        // preds stream: all-cells 0.5*conf^2 (channels 4 and 9).
#pragma unroll
        for (int j = 0; j < 4; ++j) {
            int c = c0 + j; if (c >= 30) c -= 30;
            if (c == 4 || c == 9) {
                const float v = pv[j];
                acc += 0.5f * v * v;
            }
        }

        // truths stream: obj detection on channel 4; rare (~8% of cells)
        // divergent tail gathers the full cell (240 B, cache-warm) and
        // swaps in the exact obj-cell loss.
#pragma unroll
        for (int j = 0; j < 4; ++j) {
            int c = c0 + j; if (c >= 30) c -= 30;
            if (c == 4 && tv[j] > 0.0f) {
                const int cell = (f + j) / 30;
                const float* p = preds  + cell * CCH;
                const float* t = truths + cell * CCH;
                const float p4 = p[4], p9 = p[9];
                acc += cell_loss(p, t) - 0.5f * (p4 * p4 + p9 * p9);
            }
        }
    }

    // Per-thread acc -> wave shuffle -> LDS across waves -> one atomic/block.
#pragma unroll
    for (int off = 32; off > 0; off >>= 1) acc += __shfl_down(acc, off, 64);
    if (lane == 0) wsum[wave] = acc;
    __syncthreads();
    if (tid == 0) {
        const float s = (wsum[0] + wsum[1]) + (wsum[2] + wsum[3]);
        atomicAdd(out, s * (1.0f / 4096.0f));
    }
}

extern "C" void kernel_launch(void* const* d_in, const int* in_sizes, int n_in,
                              void* d_out, int out_size, void* d_ws, size_t ws_size,
                              hipStream_t stream) {
    const float* preds  = (const float*)d_in[0];
    const float* truths = (const float*)d_in[1];
    float* out = (float*)d_out;

    const int nf4 = in_sizes[0] / 4;           // 6,021,120 float4 per tensor

    yolo_zero_kernel<<<(out_size + 255) / 256, 256, 0, stream>>>(out, out_size);
    yolo_loss_kernel<<<NBLK, NTHR, 0, stream>>>(preds, truths, out, nf4);
}